// Round 1
// baseline (1893.303 us; speedup 1.0000x reference)
//
#include <hip/hip_runtime.h>
#include <cstdint>

typedef unsigned short ushort_t;
typedef __bf16 bf16x8 __attribute__((ext_vector_type(8)));
typedef float f32x4 __attribute__((ext_vector_type(4)));

// ---- constants for this problem ----
// B=128, T=25, E=512, H=1024, V=32000, ENC=400
// K (padded input dim) = 1024 everywhere.

__device__ __forceinline__ ushort_t f2bf(float f) {
    unsigned u = __float_as_uint(f);
    unsigned r = (u + 0x7fffu + ((u >> 16) & 1u)) >> 16;
    return (ushort_t)r;
}

// ---------------- conversion / setup kernels ----------------

// float -> bf16, 4 elements per thread, n multiple of 4
__global__ void cvt4(const float* __restrict__ S, ushort_t* __restrict__ D, int n) {
    int i = (blockIdx.x * 256 + threadIdx.x) * 4;
    if (i >= n) return;
    float4 v = *(const float4*)(S + i);
    ushort4 o;
    o.x = f2bf(v.x); o.y = f2bf(v.y); o.z = f2bf(v.z); o.w = f2bf(v.w);
    *(ushort4*)(D + i) = o;
}

// W_ih [4096,912] -> bf16 padded [4096,1024]
__global__ void cvt_wih(const float* __restrict__ W, ushort_t* __restrict__ D) {
    int idx = blockIdx.x * 256 + threadIdx.x;   // 4096*1024
    int row = idx >> 10, col = idx & 1023;
    D[idx] = (col < 912) ? f2bf(W[row * 912 + col]) : (ushort_t)0;
}

// X_all bf16 [3200,1024]: row r = t*128+b; cols 0..511 word emb, 512..911 features, rest 0
__global__ void build_xall(const float* __restrict__ features, const int* __restrict__ captions,
                           const float* __restrict__ embW, ushort_t* __restrict__ X) {
    int idx = blockIdx.x * 256 + threadIdx.x;   // 3200*1024
    int r = idx >> 10, col = idx & 1023;
    int t = r >> 7, b = r & 127;
    float v;
    if (col < 512) {
        int tok = (t == 0) ? 1 : captions[b * 25 + (t - 1)];
        v = embW[tok * 512 + col];
    } else if (col < 912) {
        v = features[b * 400 + (col - 512)];
    } else {
        v = 0.f;
    }
    X[idx] = f2bf(v);
}

// ---------------- LSTM cell ----------------
// gates [128,4096] f32 (= gates_in[t] + h@W_hh^T), c [128,1024] f32
__global__ void lstm_cell(const float* __restrict__ gates,
                          const float* __restrict__ bi, const float* __restrict__ bh,
                          float* __restrict__ c, ushort_t* __restrict__ h_cur,
                          ushort_t* __restrict__ Hall, int t) {
    int idx = blockIdx.x * 256 + threadIdx.x;   // 131072
    int b = idx >> 10, u = idx & 1023;
    const float* g = gates + b * 4096;
    float vi = g[u]        + bi[u]        + bh[u];
    float vf = g[u + 1024] + bi[u + 1024] + bh[u + 1024];
    float vg = g[u + 2048] + bi[u + 2048] + bh[u + 2048];
    float vo = g[u + 3072] + bi[u + 3072] + bh[u + 3072];
    float si = 1.f / (1.f + expf(-vi));
    float sf = 1.f / (1.f + expf(-vf));
    float so = 1.f / (1.f + expf(-vo));
    float cn = sf * c[idx] + si * tanhf(vg);
    float hn = so * tanhf(cn);
    c[idx] = cn;
    ushort_t hb = f2bf(hn);
    h_cur[idx] = hb;
    if (t >= 1) Hall[(t - 1) * 131072 + idx] = hb;
}

// ---------------- bf16 GEMM, C = A * B^T (+epilogue) ----------------
// A: [M,K] bf16 row-major, B: [N,K] bf16 row-major, K multiple of 64 (=1024 here).
// Tile 128x128, BK=64, 256 threads = 4 waves, each wave 64x64 via 4x4 mfma 16x16x32.
// Staging: global_load_lds 16B/lane with XOR swizzle applied to the GLOBAL source
// chunk (LDS dest stays lane-linear, as global_load_lds requires).
// mode 0: C[gm*ldc+gn] = acc
// mode 1: C[gm*ldc+gn] = acc + addsrc[gm*ldc+gn]
// mode 2: out[(gm&127)*24*32000 + (gm>>7)*32000 + gn] = acc + bias[gn]
__global__ __launch_bounds__(256)
void gemm_bt(const ushort_t* __restrict__ A, const ushort_t* __restrict__ B,
             float* __restrict__ C, const float* __restrict__ addsrc,
             const float* __restrict__ bias, int K, int mode) {
    const int ldc  = gridDim.x * 128;
    const int bm   = blockIdx.y, bn = blockIdx.x;
    const int tid  = threadIdx.x;
    const int wave = tid >> 6, lane = tid & 63;

    __shared__ __align__(16) ushort_t As[128 * 64];
    __shared__ __align__(16) ushort_t Bs[128 * 64];

    const ushort_t* Ab = A + (size_t)bm * 128 * K;
    const ushort_t* Bb = B + (size_t)bn * 128 * K;

    f32x4 acc[4][4] = {};

    const int wm = (wave & 1) * 64;
    const int wn = (wave >> 1) * 64;

    for (int k0 = 0; k0 < K; k0 += 64) {
#pragma unroll
        for (int ro = 0; ro < 4; ++ro) {
            int L   = ro * 256 + tid;       // 0..1023 chunk index (16B chunks)
            int row = L >> 3;               // 0..127
            int cs  = (L & 7) ^ (row & 7);  // swizzled source chunk within row
            const ushort_t* ga = Ab + row * K + k0 + cs * 8;
            const ushort_t* gb = Bb + row * K + k0 + cs * 8;
            __builtin_amdgcn_global_load_lds(
                (const __attribute__((address_space(1))) void*)ga,
                (__attribute__((address_space(3))) void*)(As + L * 8), 16, 0, 0);
            __builtin_amdgcn_global_load_lds(
                (const __attribute__((address_space(1))) void*)gb,
                (__attribute__((address_space(3))) void*)(Bs + L * 8), 16, 0, 0);
        }
        __syncthreads();   // drains vmcnt(0) then barrier -> LDS ready

#pragma unroll
        for (int kk = 0; kk < 2; ++kk) {
            bf16x8 af[4], bfr[4];
#pragma unroll
            for (int mt = 0; mt < 4; ++mt) {
                int row = wm + mt * 16 + (lane & 15);
                int cc  = (kk * 4 + (lane >> 4)) ^ (row & 7);
                af[mt]  = *(const bf16x8*)(As + row * 64 + cc * 8);
            }
#pragma unroll
            for (int nt = 0; nt < 4; ++nt) {
                int row = wn + nt * 16 + (lane & 15);
                int cc  = (kk * 4 + (lane >> 4)) ^ (row & 7);
                bfr[nt] = *(const bf16x8*)(Bs + row * 64 + cc * 8);
            }
#pragma unroll
            for (int mt = 0; mt < 4; ++mt)
#pragma unroll
                for (int nt = 0; nt < 4; ++nt)
                    acc[mt][nt] = __builtin_amdgcn_mfma_f32_16x16x32_bf16(
                        af[mt], bfr[nt], acc[mt][nt], 0, 0, 0);
        }
        __syncthreads();   // protect LDS before next stage overwrites
    }

    // epilogue: C/D layout col=lane&15, row=(lane>>4)*4+reg (m89/m91-verified)
    const int r0 = (lane >> 4) * 4;
    const int cn = lane & 15;
#pragma unroll
    for (int mt = 0; mt < 4; ++mt) {
#pragma unroll
        for (int nt = 0; nt < 4; ++nt) {
#pragma unroll
            for (int r = 0; r < 4; ++r) {
                int m  = wm + mt * 16 + r0 + r;
                int n  = wn + nt * 16 + cn;
                int gm = bm * 128 + m;
                int gn = bn * 128 + n;
                float v = acc[mt][nt][r];
                if (mode == 0) {
                    C[(size_t)gm * ldc + gn] = v;
                } else if (mode == 1) {
                    C[(size_t)gm * ldc + gn] = v + addsrc[(size_t)gm * ldc + gn];
                } else {
                    // gm = (t-1)*128 + b -> out[b, t-1, gn]
                    C[(size_t)(gm & 127) * (24 * 32000) + (size_t)(gm >> 7) * 32000 + gn]
                        = v + bias[gn];
                }
            }
        }
    }
}

// ---------------- launch ----------------

extern "C" void kernel_launch(void* const* d_in, const int* in_sizes, int n_in,
                              void* d_out, int out_size, void* d_ws, size_t ws_size,
                              hipStream_t stream) {
    const float* features = (const float*)d_in[0];
    const int*   captions = (const int*)d_in[1];
    const float* emb_W    = (const float*)d_in[2];
    const float* W_ih     = (const float*)d_in[3];
    const float* W_hh     = (const float*)d_in[4];
    const float* b_ih     = (const float*)d_in[5];
    const float* b_hh     = (const float*)d_in[6];
    // d_in[7..12]: attention weights — provably dead code (softmax over 1 pixel)
    const float* fcn_W    = (const float*)d_in[13];
    const float* fcn_b    = (const float*)d_in[14];
    float* out = (float*)d_out;

    char* p = (char*)d_ws;
    auto alloc = [&](size_t bytes) { void* r = p; p += bytes; return r; };
    ushort_t* Xall     = (ushort_t*)alloc((size_t)3200 * 1024 * 2);   // 6.55 MB
    ushort_t* Wihb     = (ushort_t*)alloc((size_t)4096 * 1024 * 2);   // 8.39 MB
    ushort_t* Whhb     = (ushort_t*)alloc((size_t)4096 * 1024 * 2);   // 8.39 MB
    ushort_t* Fcnb     = (ushort_t*)alloc((size_t)32000 * 1024 * 2);  // 65.5 MB
    float*    gates_in = (float*)alloc((size_t)3200 * 4096 * 4);      // 52.4 MB
    float*    gates_bf = (float*)alloc((size_t)128 * 4096 * 4);       // 2.1 MB
    ushort_t* Hall     = (ushort_t*)alloc((size_t)3072 * 1024 * 2);   // 6.29 MB
    ushort_t* h_cur    = (ushort_t*)alloc((size_t)128 * 1024 * 2);
    float*    cbuf     = (float*)alloc((size_t)128 * 1024 * 4);
    (void)ws_size; (void)n_in; (void)in_sizes; (void)out_size;

    // zero recurrent state (ws is poisoned 0xAA before every timed launch)
    hipMemsetAsync(h_cur, 0, (size_t)128 * 1024 * 2, stream);
    hipMemsetAsync(cbuf,  0, (size_t)128 * 1024 * 4, stream);

    // weight conversions + X_all
    build_xall<<<(3200 * 1024) / 256, 256, 0, stream>>>(features, captions, emb_W, Xall);
    cvt_wih<<<(4096 * 1024) / 256, 256, 0, stream>>>(W_ih, Wihb);
    cvt4<<<(4096 * 1024) / 1024, 256, 0, stream>>>(W_hh, Whhb, 4096 * 1024);
    cvt4<<<(32000 * 1024) / 1024, 256, 0, stream>>>(fcn_W, Fcnb, 32000 * 1024);

    // gates_in[3200,4096] = X_all @ W_ih_pad^T
    gemm_bt<<<dim3(32, 25), 256, 0, stream>>>(Xall, Wihb, gates_in, nullptr, nullptr, 1024, 0);

    // sequential LSTM: 25 steps
    for (int t = 0; t < 25; ++t) {
        gemm_bt<<<dim3(32, 1), 256, 0, stream>>>(h_cur, Whhb, gates_bf,
                                                 gates_in + (size_t)t * 128 * 4096,
                                                 nullptr, 1024, 1);
        lstm_cell<<<512, 256, 0, stream>>>(gates_bf, b_ih, b_hh, cbuf, h_cur, Hall, t);
    }

    // out[b, t-1, :] = Hall @ fcn_W^T + fcn_b
    gemm_bt<<<dim3(250, 24), 256, 0, stream>>>(Hall, Fcnb, out, nullptr, fcn_b, 1024, 2);
}